// Round 9
// baseline (245.752 us; speedup 1.0000x reference)
//
#include <hip/hip_runtime.h>
#include <hip/hip_bf16.h>
#include <hip/hip_fp16.h>

#define EPS 1e-8f
#define PI_F 3.14159265358979323846f

typedef _Float16 half8 __attribute__((ext_vector_type(8)));
typedef float f32x4 __attribute__((ext_vector_type(4)));
typedef float f32x2 __attribute__((ext_vector_type(2)));

__device__ __forceinline__ float gelu_exact(float v) {
    return 0.5f * v * (1.0f + erff(v * 0.70710678118654752f));
}

// ---------------------------------------------------------------------------
// Kernel 0 (r1/r6 verbatim, measured-best pairing with the 70us gemm):
// embed_w [256 k,512 col] fp32 -> fragment-ordered fp16 hi/lo tiles
// [g(4)][kt(8)][r(128)][k(32)]; r = (dl>>5)*64 + h12*32 + (dl&31) so
// nt=0/1 -> h1 of d0/d0+16, nt=2/3 -> h2 of d0/d0+16 (d0 = g*64+wn*32+ln).
// Also zero-inits XMsum/YMsum/pooled (contiguous 49152 floats).
// ---------------------------------------------------------------------------
__global__ void convertW(const float* __restrict__ W,
                         _Float16* __restrict__ Wth, _Float16* __restrict__ Wtl,
                         float* __restrict__ zero_base) {
    int idx = blockIdx.x * 256 + threadIdx.x;   // 0..131071
    if (idx < 49152) zero_base[idx] = 0.f;      // XMsum,YMsum,pooled
    int col = idx & 511, k = idx >> 9;
    int d  = col & 255;
    int g  = d >> 6;
    int dl = d & 63;
    int r  = (dl >> 5) * 64 + ((col >> 8) << 5) + (dl & 31);
    int kt = k >> 5, ko = k & 31;
    float f = W[k * 512 + col];
    _Float16 h = (_Float16)f;
    int o = ((g * 8 + kt) * 128 + r) * 32 + ko;
    Wth[o] = h;
    Wtl[o] = (_Float16)(f - (float)h);
}

// ---------------------------------------------------------------------------
// Kernel 1: embed GEMM (r1 structure, measured 70us) + ONE contained change:
// BK=64 -- stage TWO kt per barrier pair ([128][64] A-tile, 32KB LDS).
// Barrier crossings halve (16 -> 8): the ~400cy vmcnt drain exposed at each
// barrier is paid half as often. Nothing held in registers across barriers
// (round-2's spill failure mode avoided); B fragments loaded per kt-half
// from the precomputed fp16 tables (round-8 showed in-kernel W split costs
// +12us of VALU). MFMA kt order per accumulator unchanged -> bit-identical.
// XCD swizzle unchanged: 4 g-blocks of one m-tile co-resident on one XCD.
// ---------------------------------------------------------------------------
__global__ __launch_bounds__(256, 4) void gemm_embed(
    const float* __restrict__ x,
    const _Float16* __restrict__ Wth, const _Float16* __restrict__ Wtl,
    const float* __restrict__ bias,
    unsigned short* __restrict__ XY8,
    float* __restrict__ XMsum, float* __restrict__ YMsum)
{
    __shared__ __attribute__((aligned(16))) _Float16 Ah[8192], Al[8192];
    const int tid  = threadIdx.x;
    const int wave = tid >> 6;
    const int lane = tid & 63;
    const int wm   = wave >> 1;              // m-half of the 128 rows
    const int wn   = wave & 1;               // n-half of the 128 B-rows
    const int id   = blockIdx.x;
    const int xcd  = id & 7;
    const int s    = id >> 3;
    const int g    = s & 3;                  // d-range [64g, 64g+64)
    const int mt   = (s >> 2) * 8 + xcd;     // 0..511
    const int m0   = mt * 128;
    const int q    = lane >> 4, ln = lane & 15;

    f32x4 acc[4][4];
#pragma unroll
    for (int mi = 0; mi < 4; ++mi)
#pragma unroll
        for (int nt = 0; nt < 4; ++nt)
            acc[mi][nt] = (f32x4){0.f, 0.f, 0.f, 0.f};

#pragma unroll 1
    for (int kp = 0; kp < 4; ++kp) {
        // ---- B fragments for half 0 (L2-resident fp16 tables), issued
        //      before barrier1 so their latency overlaps the barrier wait ----
        half8 bh0[4], bl0[4];
        {
            const int tbase = (g * 8 + 2 * kp) * 4096;
#pragma unroll
            for (int nt = 0; nt < 4; ++nt) {
                int off = tbase + (wn * 64 + nt * 16 + ln) * 32 + q * 8;
                bh0[nt] = *(const half8*)(Wth + off);
                bl0[nt] = *(const half8*)(Wtl + off);
            }
        }
        __syncthreads();   // barrier1: previous kt-pair's LDS readers done
        // ---- stage A tile [128 m][64 k] (both halves): fp32 -> hi + lo ----
#pragma unroll
        for (int h = 0; h < 2; ++h) {
#pragma unroll
            for (int L = 0; L < 2; ++L) {
                int idx2 = L * 256 + tid;
                int r = idx2 >> 2, cq = idx2 & 3;
                const float* src = x + (size_t)(m0 + r) * 256 + (2 * kp + h) * 32 + cq * 8;
                const float4 f0 = *(const float4*)(src);
                const float4 f1 = *(const float4*)(src + 4);
                half8 hh, ll;
                hh[0] = (_Float16)f0.x; ll[0] = (_Float16)(f0.x - (float)hh[0]);
                hh[1] = (_Float16)f0.y; ll[1] = (_Float16)(f0.y - (float)hh[1]);
                hh[2] = (_Float16)f0.z; ll[2] = (_Float16)(f0.z - (float)hh[2]);
                hh[3] = (_Float16)f0.w; ll[3] = (_Float16)(f0.w - (float)hh[3]);
                hh[4] = (_Float16)f1.x; ll[4] = (_Float16)(f1.x - (float)hh[4]);
                hh[5] = (_Float16)f1.y; ll[5] = (_Float16)(f1.y - (float)hh[5]);
                hh[6] = (_Float16)f1.z; ll[6] = (_Float16)(f1.z - (float)hh[6]);
                hh[7] = (_Float16)f1.w; ll[7] = (_Float16)(f1.w - (float)hh[7]);
                int pos = cq ^ ((r >> 1) & 3);
                *(half8*)&Ah[h * 4096 + r * 32 + pos * 8] = hh;
                *(half8*)&Al[h * 4096 + r * 32 + pos * 8] = ll;
            }
        }
        __syncthreads();   // barrier2: tile ready

        // ================= half 0 (kt = 2*kp) =================
        {
            half8 am[4];
#pragma unroll
            for (int mi = 0; mi < 4; ++mi) {
                int row = wm * 64 + mi * 16 + ln;
                am[mi] = *(const half8*)&Ah[row * 32 + (q ^ ((row >> 1) & 3)) * 8];
            }
#pragma unroll
            for (int mi = 0; mi < 4; ++mi)
#pragma unroll
                for (int nt = 0; nt < 4; ++nt)
                    acc[mi][nt] = __builtin_amdgcn_mfma_f32_16x16x32_f16(am[mi], bh0[nt], acc[mi][nt], 0, 0, 0);
#pragma unroll
            for (int mi = 0; mi < 4; ++mi)
#pragma unroll
                for (int nt = 0; nt < 4; ++nt)
                    acc[mi][nt] = __builtin_amdgcn_mfma_f32_16x16x32_f16(am[mi], bl0[nt], acc[mi][nt], 0, 0, 0);
#pragma unroll
            for (int mi = 0; mi < 4; ++mi) {
                int row = wm * 64 + mi * 16 + ln;
                half8 alv = *(const half8*)&Al[row * 32 + (q ^ ((row >> 1) & 3)) * 8];
#pragma unroll
                for (int nt = 0; nt < 4; ++nt)
                    acc[mi][nt] = __builtin_amdgcn_mfma_f32_16x16x32_f16(alv, bh0[nt], acc[mi][nt], 0, 0, 0);
            }
        }
        // ================= half 1 (kt = 2*kp+1) =================
        {
            half8 bh1[4], bl1[4];
            const int tbase = (g * 8 + 2 * kp + 1) * 4096;
#pragma unroll
            for (int nt = 0; nt < 4; ++nt) {
                int off = tbase + (wn * 64 + nt * 16 + ln) * 32 + q * 8;
                bh1[nt] = *(const half8*)(Wth + off);
                bl1[nt] = *(const half8*)(Wtl + off);
            }
            half8 am[4];
#pragma unroll
            for (int mi = 0; mi < 4; ++mi) {
                int row = wm * 64 + mi * 16 + ln;
                am[mi] = *(const half8*)&Ah[4096 + row * 32 + (q ^ ((row >> 1) & 3)) * 8];
            }
#pragma unroll
            for (int mi = 0; mi < 4; ++mi)
#pragma unroll
                for (int nt = 0; nt < 4; ++nt)
                    acc[mi][nt] = __builtin_amdgcn_mfma_f32_16x16x32_f16(am[mi], bh1[nt], acc[mi][nt], 0, 0, 0);
#pragma unroll
            for (int mi = 0; mi < 4; ++mi)
#pragma unroll
                for (int nt = 0; nt < 4; ++nt)
                    acc[mi][nt] = __builtin_amdgcn_mfma_f32_16x16x32_f16(am[mi], bl1[nt], acc[mi][nt], 0, 0, 0);
#pragma unroll
            for (int mi = 0; mi < 4; ++mi) {
                int row = wm * 64 + mi * 16 + ln;
                half8 alv = *(const half8*)&Al[4096 + row * 32 + (q ^ ((row >> 1) & 3)) * 8];
#pragma unroll
                for (int nt = 0; nt < 4; ++nt)
                    acc[mi][nt] = __builtin_amdgcn_mfma_f32_16x16x32_f16(alv, bh1[nt], acc[mi][nt], 0, 0, 0);
            }
        }
    }

    // ---- epilogue (r1 verbatim) ----
    // nt=0 -> h1 of d0, nt=1 -> h1 of d1, nt=2 -> h2 of d0, nt=3 -> h2 of d1,
    // d0 = g*64 + wn*32 + ln, d1 = d0 + 16.
    // C/D layout: col = lane&15, row = (lane>>4)*4 + reg  [m89 verified]
    const int d0 = g * 64 + wn * 32 + ln;
    const int d1 = d0 + 16;
    const int b  = m0 >> 10;
    const float b1_0 = bias[d0],       b1_1 = bias[d1];
    const float b2_0 = bias[256 + d0], b2_1 = bias[256 + d1];
    float sx0 = 0.f, sy0 = 0.f, sx1 = 0.f, sy1 = 0.f;
#pragma unroll
    for (int mi = 0; mi < 4; ++mi) {
#pragma unroll
        for (int i = 0; i < 4; ++i) {
            const int row = m0 + wm * 64 + mi * 16 + q * 4 + i;
            {
                const float h1 = acc[mi][0][i] + b1_0;
                const float h2 = acc[mi][2][i] + b2_0;
                const float rr = fabsf(h1) + 0.1f;
                float sv, cv;
                __sincosf(PI_F * h2, &sv, &cv);
                const float xc = rr * cv, yc = rr * sv;
                int pk = __builtin_amdgcn_cvt_pk_fp8_f32(xc, yc, 0, false);
                XY8[(size_t)row * 256 + d0] = (unsigned short)pk;
                sx0 += xc; sy0 += yc;
            }
            {
                const float h1 = acc[mi][1][i] + b1_1;
                const float h2 = acc[mi][3][i] + b2_1;
                const float rr = fabsf(h1) + 0.1f;
                float sv, cv;
                __sincosf(PI_F * h2, &sv, &cv);
                const float xc = rr * cv, yc = rr * sv;
                int pk = __builtin_amdgcn_cvt_pk_fp8_f32(xc, yc, 0, false);
                XY8[(size_t)row * 256 + d1] = (unsigned short)pk;
                sx1 += xc; sy1 += yc;
            }
        }
    }
    sx0 += __shfl_down(sx0, 32); sx0 += __shfl_down(sx0, 16);
    sy0 += __shfl_down(sy0, 32); sy0 += __shfl_down(sy0, 16);
    sx1 += __shfl_down(sx1, 32); sx1 += __shfl_down(sx1, 16);
    sy1 += __shfl_down(sy1, 32); sy1 += __shfl_down(sy1, 16);
    if (lane < 16) {
        atomicAdd(&XMsum[b * 256 + d0], sx0);
        atomicAdd(&YMsum[b * 256 + d0], sy0);
        atomicAdd(&XMsum[b * 256 + d1], sx1);
        atomicAdd(&YMsum[b * 256 + d1], sy1);
    }
}

// ---------------------------------------------------------------------------
// Kernel 2 (r8 tail adapted to XMsum): fused layers + pool. Grid (64 b, 8
// d-eighths); each block EXCLUSIVELY owns (b, 32 d's): full 512-block layers
// parallelism, one sweep; DX/DY in LDS; pooled via plain exclusive stores.
// ---------------------------------------------------------------------------
__global__ __launch_bounds__(256) void tail_kernel(
    const float* __restrict__ XMsum, const float* __restrict__ YMsum,
    const float* __restrict__ mw1, const float* __restrict__ mb1,
    const float* __restrict__ mw2, const float* __restrict__ mb2,
    const float* __restrict__ pw1, const float* __restrict__ pb1,
    const float* __restrict__ pw2, const float* __restrict__ pb2,
    const unsigned short* __restrict__ XY8,
    float* __restrict__ pooled)
{
    __shared__ float s_mw1[256], s_mb1[256], s_mw2[256], s_mb2[8];
    __shared__ float s_pw1[512], s_pb1[256], s_pw2[512], s_pb2[16];
    __shared__ float dxl[32], dyl[32];
    __shared__ float red[256][9];
    const int b = blockIdx.x, q8 = blockIdx.y, tid = threadIdx.x;

    s_mw1[tid] = mw1[tid]; s_mb1[tid] = mb1[tid];
    s_mw2[tid] = mw2[tid]; s_pb1[tid] = pb1[tid];
    s_pw1[tid] = pw1[tid]; s_pw1[256 + tid] = pw1[256 + tid];
    s_pw2[tid] = pw2[tid]; s_pw2[256 + tid] = pw2[256 + tid];
    if (tid < 8)  s_mb2[tid] = mb2[tid];
    if (tid < 16) s_pb2[tid] = pb2[tid];
    __syncthreads();

    // ---- layers phase: 32 d x 8 subs = 256 threads, one sweep ----
    {
        const int sub  = tid & 7;                  // k-eighth
        const int dloc = tid >> 3;                 // 0..31
        const int idx  = b * 256 + q8 * 32 + dloc;
        float xm = XMsum[idx] * (1.0f / 1024.0f);
        float ym = YMsum[idx] * (1.0f / 1024.0f);
        float dxa = 0.f, dya = 0.f;
#pragma unroll 1
        for (int i = 0; i < 8; ++i) {
            float r2    = xm * xm + ym * ym;
            float r_agg = sqrtf(r2 + EPS);
            float hyp   = sqrtf(r2);
            float inv   = hyp > 0.f ? 1.0f / hyp : 0.f;
            float st    = ym * inv;
            float ct    = hyp > 0.f ? xm * inv : 1.0f;
            float log_r = logf(r_agg + EPS);
            float lr = 0.f, p0 = 0.f, p1 = 0.f;
#pragma unroll
            for (int k4 = 0; k4 < 4; ++k4) {
                int k = sub * 4 + k4;
                float hm = gelu_exact(log_r * s_mw1[i * 32 + k] + s_mb1[i * 32 + k]);
                lr += hm * s_mw2[i * 32 + k];
                float hp = gelu_exact(st * s_pw1[i * 64 + k] + ct * s_pw1[i * 64 + 32 + k] + s_pb1[i * 32 + k]);
                p0 += hp * s_pw2[i * 64 + 2 * k + 0];
                p1 += hp * s_pw2[i * 64 + 2 * k + 1];
            }
            lr += __shfl_xor(lr, 1); lr += __shfl_xor(lr, 2); lr += __shfl_xor(lr, 4);
            p0 += __shfl_xor(p0, 1); p0 += __shfl_xor(p0, 2); p0 += __shfl_xor(p0, 4);
            p1 += __shfl_xor(p1, 1); p1 += __shfl_xor(p1, 2); p1 += __shfl_xor(p1, 4);
            lr += s_mb2[i];
            p0 += s_pb2[i * 2 + 0];
            p1 += s_pb2[i * 2 + 1];
            float r_trans = expf(lr);
            float hp2  = sqrtf(p0 * p0 + p1 * p1);
            float invp = hp2 > 0.f ? 1.0f / hp2 : 0.f;
            float ctt  = hp2 > 0.f ? p1 * invp : 1.0f;
            float stt  = p0 * invp;
            float dx = r_trans * ctt;
            float dy = r_trans * stt;
            dxa += dx; dya += dy; xm += dx; ym += dy;
        }
        if (sub == 0) { dxl[dloc] = dxa; dyl[dloc] = dya; }
    }
    __syncthreads();

    // ---- pool phase: 32 d x 1024 s per block ----
    {
        const int dg = tid & 3;            // d-octet: d = q8*32 + dg*8 ..+7
        const int sh = tid >> 2;           // 0..63: rows sh*16 .. sh*16+15
        const int d0 = q8 * 32 + dg * 8;
        float dxv[8], dyv[8], sacc[8];
#pragma unroll
        for (int j = 0; j < 8; ++j) {
            dxv[j] = dxl[dg * 8 + j];
            dyv[j] = dyl[dg * 8 + j];
            sacc[j] = 0.f;
        }
        const size_t base = ((size_t)b * 1024 + sh * 16) * 256 + d0;
#pragma unroll 4
        for (int i = 0; i < 16; ++i) {
            const int4 v = *(const int4*)(XY8 + base + (size_t)i * 256);
            const int wv[4] = {v.x, v.y, v.z, v.w};
#pragma unroll
            for (int w = 0; w < 4; ++w) {
                f32x2 pa = __builtin_amdgcn_cvt_pk_f32_fp8(wv[w], false);
                f32x2 pb = __builtin_amdgcn_cvt_pk_f32_fp8(wv[w], true);
                float xa = pa[0] + dxv[2 * w],     ya = pa[1] + dyv[2 * w];
                float xb = pb[0] + dxv[2 * w + 1], yb = pb[1] + dyv[2 * w + 1];
                sacc[2 * w]     += sqrtf(xa * xa + ya * ya + EPS);
                sacc[2 * w + 1] += sqrtf(xb * xb + yb * yb + EPS);
            }
        }
#pragma unroll
        for (int j = 0; j < 8; ++j) red[tid][j] = sacc[j];
    }
    __syncthreads();
    if (tid < 32) {
        const int dgq = tid >> 3, j = tid & 7;
        float t = 0.f;
#pragma unroll
        for (int c = 0; c < 64; ++c) t += red[c * 4 + dgq][j];
        pooled[b * 256 + q8 * 32 + dgq * 8 + j] = t;
    }
}

// ---------------------------------------------------------------------------
// Kernel 3 (verbatim): classifier, n-dim sliced over blockIdx.y.
// ---------------------------------------------------------------------------
__global__ __launch_bounds__(256) void cls_kernel(
    const float* __restrict__ pooled,
    const float* __restrict__ w1, const float* __restrict__ b1,
    const float* __restrict__ w2, const float* __restrict__ b2,
    float* __restrict__ out)
{
    __shared__ float pl[256];
    __shared__ float part[8][32];
    __shared__ float hd[32];
    const int b = blockIdx.x, yc = blockIdx.y, tid = threadIdx.x;
    pl[tid] = pooled[b * 256 + tid] * (1.0f / 1024.0f);
    __syncthreads();
    const int hu = tid & 31, kc = tid >> 5;
    float a = 0.f;
    for (int k = kc * 32; k < kc * 32 + 32; ++k) a += pl[k] * w1[k * 32 + hu];
    part[kc][hu] = a;
    __syncthreads();
    if (tid < 32) {
        float s = b1[tid];
#pragma unroll
        for (int c = 0; c < 8; ++c) s += part[c][tid];
        hd[tid] = gelu_exact(s);
    }
    __syncthreads();
    const int n0 = yc * 250;
    const int nend = (n0 + 250 < 1000) ? n0 + 250 : 1000;
    for (int n = n0 + tid; n < nend; n += 256) {
        float s = b2[n];
#pragma unroll
        for (int k = 0; k < 32; ++k) s += hd[k] * w2[k * 1000 + n];
        out[b * 1000 + n] = s;
    }
}

// ---------------------------------------------------------------------------
extern "C" void kernel_launch(void* const* d_in, const int* in_sizes, int n_in,
                              void* d_out, int out_size, void* d_ws, size_t ws_size,
                              hipStream_t stream)
{
    const float* x       = (const float*)d_in[0];
    const float* embed_w = (const float*)d_in[1];
    const float* embed_b = (const float*)d_in[2];
    const float* mag_w1  = (const float*)d_in[3];
    const float* mag_b1  = (const float*)d_in[4];
    const float* mag_w2  = (const float*)d_in[5];
    const float* mag_b2  = (const float*)d_in[6];
    const float* ph_w1   = (const float*)d_in[7];
    const float* ph_b1   = (const float*)d_in[8];
    const float* ph_w2   = (const float*)d_in[9];
    const float* ph_b2   = (const float*)d_in[10];
    const float* cls_w1  = (const float*)d_in[11];
    const float* cls_b1  = (const float*)d_in[12];
    const float* cls_w2  = (const float*)d_in[13];
    const float* cls_b2  = (const float*)d_in[14];
    float* out = (float*)d_out;

    char* ws = (char*)d_ws;
    unsigned short* XY8 = (unsigned short*)(ws + 0);   // 33554432 B (fp8 pairs)
    _Float16* Wth = (_Float16*)(ws + 33554432);        // 262144
    _Float16* Wtl = (_Float16*)(ws + 33816576);        // 262144
    float* XMsum  = (float*)(ws + 34078720);           // 65536
    float* YMsum  = (float*)(ws + 34144256);           // 65536
    float* pooled = (float*)(ws + 34209792);           // 65536

    convertW<<<512, 256, 0, stream>>>(embed_w, Wth, Wtl, XMsum);  // zeros XMsum,YMsum,pooled
    gemm_embed<<<2048, 256, 0, stream>>>(x, Wth, Wtl, embed_b, XY8, XMsum, YMsum);
    tail_kernel<<<dim3(64, 8), 256, 0, stream>>>(XMsum, YMsum,
                                                 mag_w1, mag_b1, mag_w2, mag_b2,
                                                 ph_w1, ph_b1, ph_w2, ph_b2,
                                                 XY8, pooled);
    cls_kernel<<<dim3(64, 4), 256, 0, stream>>>(pooled, cls_w1, cls_b1, cls_w2, cls_b2, out);
}